// Round 2
// 598.830 us; speedup vs baseline: 1.0362x; 1.0362x over previous
//
#include <hip/hip_runtime.h>
#include <cstdint>
#include <cstddef>

#define B_ 4
#define L_ 4096
#define H_ 16
#define D_ 128
#define HD_ (H_*D_)             // 2048
#define LHD_ ((size_t)L_*HD_)   // 8388608
#define BH_ (B_*H_)             // 64
#define EPS_ 1e-6f

typedef float f32x4 __attribute__((ext_vector_type(4)));
typedef unsigned int u32x4 __attribute__((ext_vector_type(4)));
typedef short s16x8 __attribute__((ext_vector_type(8)));

__device__ __forceinline__ unsigned short f2bf(float f){
  unsigned int u = __float_as_uint(f);
  u += 0x7fffu + ((u >> 16) & 1u);      // round-to-nearest-even
  return (unsigned short)(u >> 16);
}
__device__ __forceinline__ unsigned int pack2(float lo, float hi){
  return (unsigned int)f2bf(lo) | ((unsigned int)f2bf(hi) << 16);
}

// ---------------- Stage 1: q_global = mean_l(Q) / sqrt(2048), atomic partials
// grid 512: 2 blocks/CU -> 8 waves/CU for latency hiding
__global__ __launch_bounds__(256) void k_qmean(const float* __restrict__ Q, float* __restrict__ qg){
  int b  = blockIdx.x >> 7;
  int l0 = (blockIdx.x & 127) * 32;
  const float* base = Q + (size_t)b * LHD_ + (size_t)l0 * HD_;
  int t = threadIdx.x;
  f32x4 a0 = {0.f,0.f,0.f,0.f}, a1 = {0.f,0.f,0.f,0.f};
  #pragma unroll 4
  for (int l = 0; l < 32; ++l){
    const f32x4* row = (const f32x4*)(base + (size_t)l * HD_);
    a0 += row[t];
    a1 += row[t + 256];
  }
  const float scale = 1.0f / (4096.0f * 45.254833995939045f);  // 1/(L*sqrt(2048))
  float* dst = qg + b * HD_;
  #pragma unroll
  for (int i = 0; i < 4; ++i){
    atomicAdd(dst + 4*t + i,        a0[i] * scale);
    atomicAdd(dst + 1024 + 4*t + i, a1[i] * scale);
  }
}

// ---------------- Stage 2: scores[b,h,l] = q_global[b,h,:]·K[b,l,h,:]
// grid 1024: 4 blocks/CU
__global__ __launch_bounds__(256) void k_scores(const float* __restrict__ K, const float* __restrict__ qg,
                                                float* __restrict__ scores){
  int b  = blockIdx.x >> 8;
  int l0 = (blockIdx.x & 255) * 16;
  int t = threadIdx.x;
  int wave = t >> 6, lane = t & 63;
  // lane's j-th float4 of a 2048-float row covers h = 2j + (lane>>5), d = (lane&31)*4..+4
  f32x4 q[8];
  const f32x4* qv = (const f32x4*)(qg + b * HD_);
  #pragma unroll
  for (int j = 0; j < 8; ++j)
    q[j] = qv[(2*j + (lane >> 5)) * 32 + (lane & 31)];
  for (int li = wave; li < 16; li += 4){
    const f32x4* kv = (const f32x4*)(K + (size_t)b * LHD_ + (size_t)(l0 + li) * HD_);
    float s[8];
    #pragma unroll
    for (int j = 0; j < 8; ++j){
      f32x4 x = kv[j * 64 + lane];   // contiguous 1KB per instruction across the wave
      s[j] = x[0]*q[j][0] + x[1]*q[j][1] + x[2]*q[j][2] + x[3]*q[j][3];
    }
    #pragma unroll
    for (int off = 1; off < 32; off <<= 1){
      #pragma unroll
      for (int j = 0; j < 8; ++j) s[j] += __shfl_xor(s[j], off);
    }
    if ((lane & 31) == 0){
      int hb = lane >> 5;
      #pragma unroll
      for (int j = 0; j < 8; ++j)
        scores[(size_t)(b * H_ + 2*j + hb) * L_ + l0 + li] = s[j];
    }
  }
}

// ---------------- Stage 3: alpha = softmax_l(scores) * L, in place
__global__ __launch_bounds__(256) void k_softmax(float* __restrict__ scores){
  int bh = blockIdx.x;
  float* s = scores + (size_t)bh * L_;
  int t = threadIdx.x;
  int wave = t >> 6, lane = t & 63;
  float v[16];
  #pragma unroll
  for (int j = 0; j < 16; ++j) v[j] = s[t + 256*j];
  float m = -1e30f;
  #pragma unroll
  for (int j = 0; j < 16; ++j) m = fmaxf(m, v[j]);
  #pragma unroll
  for (int off = 1; off < 64; off <<= 1) m = fmaxf(m, __shfl_xor(m, off));
  __shared__ float red[8];
  if (lane == 0) red[wave] = m;
  __syncthreads();
  m = fmaxf(fmaxf(red[0], red[1]), fmaxf(red[2], red[3]));
  float z = 0.f;
  #pragma unroll
  for (int j = 0; j < 16; ++j) z += __expf(v[j] - m);
  #pragma unroll
  for (int off = 1; off < 64; off <<= 1) z += __shfl_xor(z, off);
  if (lane == 0) red[4 + wave] = z;
  __syncthreads();
  z = red[4] + red[5] + red[6] + red[7];
  float scale = (float)L_ / z;
  #pragma unroll
  for (int j = 0; j < 16; ++j) s[t + 256*j] = __expf(v[j] - m) * scale;
}

// ---------------- Stage 4: KV_part[c][bh] += (phi_K*alpha)^T @ V over 1024 l, bf16 MFMA.
// 512 threads (8 waves, each owns a 16-row m-strip x full 128 e) + register prefetch:
// next l-tile's global loads issue right after the LDS pack, hiding HBM latency under
// frag reads + MFMA + next barrier.
// LDS layout: row d (or e), pitch 20 words (40 bf16); k (=l) pairs packed in dwords;
// 4-word groups XOR-swizzled by (d>>2)&3 to break write conflicts.
__global__ __launch_bounds__(512) void k_kv(const float* __restrict__ phiK, const float* __restrict__ V,
                                            const float* __restrict__ alpha,
                                            float* __restrict__ KV_part, float* __restrict__ Ksum){
  int c  = blockIdx.x & 3;
  int bh = blockIdx.x >> 2;
  int b = bh >> 4, h = bh & 15;
  __shared__ unsigned int Al[128 * 20];
  __shared__ unsigned int Bl[128 * 20];
  __shared__ float ksred[128 * 16];
  int t = threadIdx.x;
  int wave = t >> 6, lane = t & 63, q = lane >> 4, r = lane & 15;
  int d4 = t & 31, lp = t >> 5;   // staging role: 4 d-columns, l-pair index in [0,16)
  f32x4 acc[8];
  #pragma unroll
  for (int nt = 0; nt < 8; ++nt){ f32x4 z = {0.f,0.f,0.f,0.f}; acc[nt] = z; }
  float ksl[4] = {0.f,0.f,0.f,0.f};

  const size_t arow = (size_t)bh * L_;
  // prefetch kt = 0
  int gl = c * 1024 + 2 * lp;
  const float* rowK = phiK + (((size_t)b * L_ + gl) * H_ + h) * D_;
  const float* rowV = V    + (((size_t)b * L_ + gl) * H_ + h) * D_;
  f32x4 xa0 = ((const f32x4*)rowK)[d4];
  f32x4 xa1 = ((const f32x4*)(rowK + HD_))[d4];
  f32x4 xb0 = ((const f32x4*)rowV)[d4];
  f32x4 xb1 = ((const f32x4*)(rowV + HD_))[d4];
  float al0 = alpha[arow + gl];
  float al1 = alpha[arow + gl + 1];

  int cg = lp >> 2, cl = lp & 3;
  int grp = 4 * (cg ^ (d4 & 3)) + cl;

  for (int kt = 0; kt < 32; ++kt){
    __syncthreads();   // previous iter's frag reads done
    #pragma unroll
    for (int i = 0; i < 4; ++i){
      int d = 4*d4 + i;
      float w0 = xa0[i] * al0;
      float w1 = xa1[i] * al1;
      ksl[i] += w0 + w1;
      Al[d * 20 + grp] = pack2(w0, w1);
      Bl[d * 20 + grp] = pack2(xb0[i], xb1[i]);
    }
    if (kt < 31){       // issue next tile's loads; in flight during MFMA + barriers
      int gl2 = c * 1024 + (kt + 1) * 32 + 2 * lp;
      const float* nK = phiK + (((size_t)b * L_ + gl2) * H_ + h) * D_;
      const float* nV = V    + (((size_t)b * L_ + gl2) * H_ + h) * D_;
      xa0 = ((const f32x4*)nK)[d4];
      xa1 = ((const f32x4*)(nK + HD_))[d4];
      xb0 = ((const f32x4*)nV)[d4];
      xb1 = ((const f32x4*)(nV + HD_))[d4];
      al0 = alpha[arow + gl2];
      al1 = alpha[arow + gl2 + 1];
    }
    __syncthreads();
    int m = 16*wave + r;
    s16x8 af = *((const s16x8*)&Al[m * 20 + 4 * (q ^ ((m >> 2) & 3))]);
    s16x8 bf[8];
    #pragma unroll
    for (int nt = 0; nt < 8; ++nt){
      int n = 16*nt + r;
      bf[nt] = *((const s16x8*)&Bl[n * 20 + 4 * (q ^ ((n >> 2) & 3))]);
    }
    #pragma unroll
    for (int nt = 0; nt < 8; ++nt)
      acc[nt] = __builtin_amdgcn_mfma_f32_16x16x32_bf16(af, bf[nt], acc[nt], 0, 0, 0);
  }

  // write fp32 partial KV: D[m=d][n=e], row = 16*wave + 4q + reg, col = r
  size_t pb = ((size_t)c * BH_ + bh) * ((size_t)D_ * D_);
  #pragma unroll
  for (int reg = 0; reg < 4; ++reg){
    int d = 16*wave + 4*q + reg;
    float* dst = KV_part + pb + (size_t)d * D_;
    #pragma unroll
    for (int nt = 0; nt < 8; ++nt)
      dst[16*nt + r] = acc[nt][reg];
  }
  // K_sum partial reduce (fp32, pre-rounding values)
  #pragma unroll
  for (int i = 0; i < 4; ++i) ksred[(4*d4 + i) * 16 + lp] = ksl[i];
  __syncthreads();
  if (t < 128){
    float s = 0.f;
    #pragma unroll
    for (int j = 0; j < 16; ++j) s += ksred[t * 16 + j];
    atomicAdd(Ksum + (size_t)bh * D_ + t, s);
  }
}

// ---------------- Stage 4b: sum 4 partials, transpose -> KVT bf16 [bh][e][d]; K_sum -> bf16
// grid 256: one block per (bh, e-quarter); vectorized f32x4 partial sums
__global__ __launch_bounds__(256) void k_reduce(const float* __restrict__ KV_part, const float* __restrict__ Ksum,
                                                unsigned int* __restrict__ KVT, unsigned int* __restrict__ KsumT){
  int bh = blockIdx.x >> 2, eq = blockIdx.x & 3;
  int t = threadIdx.x;
  __shared__ float T[128 * 33];
  const f32x4* P0 = (const f32x4*)(KV_part + (size_t)bh * 16384);
  #pragma unroll
  for (int p = 0; p < 4; ++p){
    int i4 = p * 256 + t;            // 1024 f32x4 = 128 d-rows x 8 e-vec
    int d = i4 >> 3, e4 = i4 & 7;
    int idx = d * 32 + eq * 8 + e4;  // f32x4 index within [d][128]
    f32x4 s = P0[idx]
            + P0[idx + (size_t)1 * BH_ * 4096]
            + P0[idx + (size_t)2 * BH_ * 4096]
            + P0[idx + (size_t)3 * BH_ * 4096];
    int e = e4 * 4;
    T[d * 33 + e    ] = s[0];
    T[d * 33 + e + 1] = s[1];
    T[d * 33 + e + 2] = s[2];
    T[d * 33 + e + 3] = s[3];
  }
  __syncthreads();
  #pragma unroll
  for (int p = 0; p < 8; ++p){
    int o = p * 256 + t;             // 2048 = 32 e-rows x 64 d-pairs
    int e = o >> 6, dp = o & 63;
    KVT[(size_t)bh * 8192 + (size_t)(eq * 32 + e) * 64 + dp] =
        pack2(T[(2*dp) * 33 + e], T[(2*dp + 1) * 33 + e]);
  }
  if (eq == 0 && t < 64)
    KsumT[(size_t)bh * 64 + t] = pack2(Ksum[(size_t)bh * 128 + 2*t], Ksum[(size_t)bh * 128 + 2*t + 1]);
}

// ---------------- Stage 5: out = (phi_Q @ KV) / (phi_Q·K_sum + eps); denom as 9th n-tile
__global__ __launch_bounds__(256) void k_out(const float* __restrict__ phiQ,
                                             const unsigned int* __restrict__ KVT,
                                             const unsigned int* __restrict__ KsumT,
                                             float* __restrict__ out){
  int chunk = blockIdx.x & 31;
  int bh = blockIdx.x >> 5;
  int b = bh >> 4, h = bh & 15;
  int l0 = chunk * 128;
  __shared__ __align__(16) unsigned short BT[144 * 136];  // rows: 0-127 KV^T[e][d], 128 K_sum, 129-143 zero
  int t = threadIdx.x;
  const u32x4* src = (const u32x4*)(KVT + (size_t)bh * 8192);
  #pragma unroll
  for (int p = 0; p < 8; ++p){
    int i = p * 256 + t;             // 2048 groups of 8 bf16
    int row = i >> 4;
    int col = (i & 15) * 8;
    *((u32x4*)&BT[row * 136 + col]) = src[i];
  }
  if (t < 16) *((u32x4*)&BT[128 * 136 + t * 8]) = ((const u32x4*)(KsumT + (size_t)bh * 64))[t];
  if (t < 255){ u32x4 z = {0u,0u,0u,0u}; *((u32x4*)&BT[129 * 136 + t * 8]) = z; }
  __syncthreads();

  int wave = t >> 6, lane = t & 63, q = lane >> 4, r = lane & 15;
  f32x4 accN[2][8], accD[2];
  #pragma unroll
  for (int mt = 0; mt < 2; ++mt){
    f32x4 z = {0.f,0.f,0.f,0.f};
    accD[mt] = z;
    #pragma unroll
    for (int nt = 0; nt < 8; ++nt) accN[mt][nt] = z;
  }
  const float* A0 = phiQ + (((size_t)b * L_ + (l0 + 32*wave + r)) * H_ + h) * D_ + q * 8;
  const float* A1 = A0 + (size_t)16 * HD_;
  #pragma unroll
  for (int ks = 0; ks < 4; ++ks){
    s16x8 af[2];
    #pragma unroll
    for (int mt = 0; mt < 2; ++mt){
      const float* ap = (mt ? A1 : A0) + 32 * ks;
      f32x4 x0 = *((const f32x4*)ap);
      f32x4 x1 = *((const f32x4*)(ap + 4));
      union { s16x8 s; unsigned int u[4]; } fr;
      fr.u[0] = pack2(x0[0], x0[1]);
      fr.u[1] = pack2(x0[2], x0[3]);
      fr.u[2] = pack2(x1[0], x1[1]);
      fr.u[3] = pack2(x1[2], x1[3]);
      af[mt] = fr.s;
    }
    #pragma unroll
    for (int nt = 0; nt < 9; ++nt){
      int n = 16*nt + r;
      s16x8 bf = *((const s16x8*)&BT[n * 136 + q * 8 + 32 * ks]);
      if (nt < 8){
        accN[0][nt] = __builtin_amdgcn_mfma_f32_16x16x32_bf16(af[0], bf, accN[0][nt], 0, 0, 0);
        accN[1][nt] = __builtin_amdgcn_mfma_f32_16x16x32_bf16(af[1], bf, accN[1][nt], 0, 0, 0);
      } else {
        accD[0] = __builtin_amdgcn_mfma_f32_16x16x32_bf16(af[0], bf, accD[0], 0, 0, 0);
        accD[1] = __builtin_amdgcn_mfma_f32_16x16x32_bf16(af[1], bf, accD[1], 0, 0, 0);
      }
    }
  }
  #pragma unroll
  for (int mt = 0; mt < 2; ++mt)
    #pragma unroll
    for (int reg = 0; reg < 4; ++reg){
      float den = __shfl(accD[mt][reg], (lane & 48)) + EPS_;  // col 0 of denom tile, same row
      float inv = 1.0f / den;
      int l = l0 + 32*wave + 16*mt + 4*q + reg;
      float* orow = out + (((size_t)b * L_ + l) * H_ + h) * D_;
      #pragma unroll
      for (int nt = 0; nt < 8; ++nt)
        orow[16*nt + r] = accN[nt < 8 ? mt : 0][nt][reg] * inv;
    }
}

extern "C" void kernel_launch(void* const* d_in, const int* in_sizes, int n_in,
                              void* d_out, int out_size, void* d_ws, size_t ws_size,
                              hipStream_t stream){
  const float* Q    = (const float*)d_in[0];
  const float* K    = (const float*)d_in[1];
  const float* V    = (const float*)d_in[2];
  const float* phiQ = (const float*)d_in[3];
  const float* phiK = (const float*)d_in[4];
  float* out = (float*)d_out;
  char* ws = (char*)d_ws;
  // workspace layout (20,004,864 B total)
  float* qg      = (float*)(ws);                       // 8192 f32
  float* Ksum    = (float*)(ws + 32768);               // 8192 f32
  float* scores  = (float*)(ws + 65536);               // 262144 f32 (alpha in-place)
  float* KV_part = (float*)(ws + 1114112);             // 4*64*16384 f32 = 16 MB
  unsigned int* KVT   = (unsigned int*)(ws + 17891328);  // 64*8192 u32 = 2 MB (bf16 pairs)
  unsigned int* KsumT = (unsigned int*)(ws + 19988480);  // 64*64 u32

  hipMemsetAsync(qg, 0, 65536, stream);                // zero qg + Ksum
  k_qmean  <<<512,  256, 0, stream>>>(Q, qg);
  k_scores <<<1024, 256, 0, stream>>>(K, qg, scores);
  k_softmax<<<64,   256, 0, stream>>>(scores);
  k_kv     <<<256,  512, 0, stream>>>(phiK, V, scores, KV_part, Ksum);
  k_reduce <<<256,  256, 0, stream>>>(KV_part, Ksum, KVT, KsumT);
  k_out    <<<2048, 256, 0, stream>>>(phiQ, KVT, KsumT, out);
}